// Round 2
// baseline (639.140 us; speedup 1.0000x reference)
//
#include <hip/hip_runtime.h>

// B=4, L=2048, D=1024, H=16, HD=64.
// d_in: fp32 (x, Wqkv, bqkv, Wproj, bproj). d_out: fp32.
// Internal pipeline: bf16 MFMA, bf16 Q/K/V/Y workspace.

typedef __bf16 bf16x8 __attribute__((ext_vector_type(8)));
typedef float f32x4 __attribute__((ext_vector_type(4)));

#define MFMA16(a, b, c) __builtin_amdgcn_mfma_f32_16x16x32_bf16(a, b, c, 0, 0, 0)

// ---------------------------------------------------------------------------
// QKV GEMM: C[8192,3072] = X[8192,1024] @ Wqkv[1024,3072] + bqkv,
// fp32 in, bf16 MFMA, scattered bf16 into q/k/v [B,H,L,HD] workspace.
// 128x128 tile, BK=32, 256 threads = 4 waves (2x2), each wave 64x64.
// ---------------------------------------------------------------------------
__global__ __launch_bounds__(256, 2)
void qkv_gemm_kernel(const float* __restrict__ X, const float* __restrict__ W,
                     const float* __restrict__ bias,
                     __bf16* __restrict__ qo, __bf16* __restrict__ ko,
                     __bf16* __restrict__ vo)
{
    __shared__ __bf16 As[128][40];  // [m][k], pad 32->40
    __shared__ __bf16 Bs[128][40];  // [n][k] (transposed on store)
    const int tid = threadIdx.x;
    const int lane = tid & 63;
    const int w = tid >> 6;
    const int wr = w >> 1, wc = w & 1;
    const int row = lane & 15, g = lane >> 4;
    const int m0 = blockIdx.x * 128;
    const int n0 = blockIdx.y * 128;

    const f32x4 fzero = {0.f, 0.f, 0.f, 0.f};
    f32x4 acc[4][4];
#pragma unroll
    for (int a = 0; a < 4; ++a)
#pragma unroll
        for (int b = 0; b < 4; ++b) acc[a][b] = fzero;

    for (int k0 = 0; k0 < 1024; k0 += 32) {
        __syncthreads();
        // stage A tile [128][32]: fp32 -> bf16
#pragma unroll
        for (int i = 0; i < 2; ++i) {
            int lin = i * 256 + tid;
            int ar = lin >> 2, ac = (lin & 3) * 8;
            const float* src = &X[(size_t)(m0 + ar) * 1024 + k0 + ac];
            f32x4 lo = *(const f32x4*)src;
            f32x4 hi = *(const f32x4*)(src + 4);
            bf16x8 a8;
#pragma unroll
            for (int j = 0; j < 4; ++j) { a8[j] = (__bf16)lo[j]; a8[j + 4] = (__bf16)hi[j]; }
            *(bf16x8*)&As[ar][ac] = a8;
        }
        // stage B tile [32][128] transposed -> Bs[n][k], fp32 -> bf16
#pragma unroll
        for (int i = 0; i < 2; ++i) {
            int lin = i * 256 + tid;
            int bk = lin >> 4, bn = (lin & 15) * 8;
            const float* src = &W[(size_t)(k0 + bk) * 3072 + n0 + bn];
            f32x4 lo = *(const f32x4*)src;
            f32x4 hi = *(const f32x4*)(src + 4);
#pragma unroll
            for (int j = 0; j < 4; ++j) {
                Bs[bn + j][bk] = (__bf16)lo[j];
                Bs[bn + 4 + j][bk] = (__bf16)hi[j];
            }
        }
        __syncthreads();

        bf16x8 af[4], bfr[4];
#pragma unroll
        for (int mf = 0; mf < 4; ++mf)
            af[mf] = *(const bf16x8*)&As[wr * 64 + mf * 16 + row][g * 8];
#pragma unroll
        for (int nf = 0; nf < 4; ++nf)
            bfr[nf] = *(const bf16x8*)&Bs[wc * 64 + nf * 16 + row][g * 8];
#pragma unroll
        for (int mf = 0; mf < 4; ++mf)
#pragma unroll
            for (int nf = 0; nf < 4; ++nf)
                acc[mf][nf] = MFMA16(af[mf], bfr[nf], acc[mf][nf]);
    }

    // epilogue: C/D layout col=lane&15, row=(lane>>4)*4+i
#pragma unroll
    for (int mf = 0; mf < 4; ++mf)
#pragma unroll
        for (int nf = 0; nf < 4; ++nf) {
            int n = n0 + wc * 64 + nf * 16 + row;
            int part = n >> 10;           // 0=q 1=k 2=v
            int d = n & 1023;
            int h = d >> 6, hd = d & 63;
            __bf16* dst = part == 0 ? qo : (part == 1 ? ko : vo);
            float bv = bias[n];
#pragma unroll
            for (int i = 0; i < 4; ++i) {
                int mm = m0 + wr * 64 + mf * 16 + g * 4 + i;
                int b = mm >> 11, l = mm & 2047;
                dst[(((size_t)(b * 16 + h) * 2048) + l) * 64 + hd] =
                    (__bf16)(acc[mf][nf][i] + bv);
            }
        }
}

// ---------------------------------------------------------------------------
// Causal flash attention. Grid: (L/128=16, B*H=64). 256 threads = 4 waves,
// wave w handles q rows [qbase+32w, qbase+32w+32). K-tile = 32 keys.
// ---------------------------------------------------------------------------
__global__ __launch_bounds__(256, 2)
void attn_kernel(const __bf16* __restrict__ Qw, const __bf16* __restrict__ Kw,
                 const __bf16* __restrict__ Vw, __bf16* __restrict__ Yw)
{
    __shared__ __bf16 Vs[64][40];      // Vs[d][k] transposed
    __shared__ __bf16 Ps[4][32][40];   // per-wave P repack [q][k]
    const int tid = threadIdx.x;
    const int lane = tid & 63;
    const int w = tid >> 6;
    const int row = lane & 15, g = lane >> 4;
    const int bh = blockIdx.y;
    const int qbase = blockIdx.x * 128;
    const int qw = qbase + w * 32;
    const __bf16* Q = Qw + (size_t)bh * 2048 * 64;
    const __bf16* K = Kw + (size_t)bh * 2048 * 64;
    const __bf16* V = Vw + (size_t)bh * 2048 * 64;

    bf16x8 qf[2][2];
#pragma unroll
    for (int q2 = 0; q2 < 2; ++q2)
#pragma unroll
        for (int dc = 0; dc < 2; ++dc)
            qf[q2][dc] = *(const bf16x8*)
                &Q[(size_t)(qw + q2 * 16 + row) * 64 + dc * 32 + g * 8];

    const f32x4 fzero = {0.f, 0.f, 0.f, 0.f};
    f32x4 O[2][4];
    float mrow[2][4], lrow[2][4];
#pragma unroll
    for (int q2 = 0; q2 < 2; ++q2) {
#pragma unroll
        for (int df = 0; df < 4; ++df) O[q2][df] = fzero;
#pragma unroll
        for (int i = 0; i < 4; ++i) {
            mrow[q2][i] = -__builtin_inff();
            lrow[q2][i] = 0.f;
        }
    }

    const int nkt = (qbase + 128) >> 5;
    for (int kt = 0; kt < nkt; ++kt) {
        const int kb = kt << 5;
        __syncthreads();
        {   // stage V tile transposed: Vs[d][k] = V[kb+k][d]
            int kk = tid >> 3, d0 = (tid & 7) * 8;
            bf16x8 v8 = *(const bf16x8*)&V[(size_t)(kb + kk) * 64 + d0];
#pragma unroll
            for (int j = 0; j < 8; ++j) Vs[d0 + j][kk] = v8[j];
        }
        __syncthreads();

        if (kb <= qw + 31) {   // wave-uniform causal skip
            f32x4 s[2][2];
#pragma unroll
            for (int q2 = 0; q2 < 2; ++q2)
#pragma unroll
                for (int kf = 0; kf < 2; ++kf) s[q2][kf] = fzero;
#pragma unroll
            for (int kf = 0; kf < 2; ++kf) {
                bf16x8 kfr[2];
#pragma unroll
                for (int dc = 0; dc < 2; ++dc)
                    kfr[dc] = *(const bf16x8*)
                        &K[(size_t)(kb + kf * 16 + row) * 64 + dc * 32 + g * 8];
#pragma unroll
                for (int q2 = 0; q2 < 2; ++q2)
#pragma unroll
                    for (int dc = 0; dc < 2; ++dc)
                        s[q2][kf] = MFMA16(qf[q2][dc], kfr[dc], s[q2][kf]);
            }
#pragma unroll
            for (int q2 = 0; q2 < 2; ++q2) {
                float pmax[4];
#pragma unroll
                for (int i = 0; i < 4; ++i) {
                    int qg = qw + q2 * 16 + g * 4 + i;
#pragma unroll
                    for (int kf = 0; kf < 2; ++kf) {
                        int kg = kb + kf * 16 + row;
                        float sv = s[q2][kf][i] * 0.125f;
                        s[q2][kf][i] = (kg > qg) ? -1e30f : sv;
                    }
                    float t = fmaxf(s[q2][0][i], s[q2][1][i]);
#pragma unroll
                    for (int msk = 1; msk <= 8; msk <<= 1)
                        t = fmaxf(t, __shfl_xor(t, msk, 64));
                    pmax[i] = t;
                }
#pragma unroll
                for (int i = 0; i < 4; ++i) {
                    float mnew = fmaxf(mrow[q2][i], pmax[i]);
                    float alpha = __expf(mrow[q2][i] - mnew);
                    float rs = 0.f;
#pragma unroll
                    for (int kf = 0; kf < 2; ++kf) {
                        float p = __expf(s[q2][kf][i] - mnew);
                        s[q2][kf][i] = p;
                        rs += p;
                    }
#pragma unroll
                    for (int msk = 1; msk <= 8; msk <<= 1)
                        rs += __shfl_xor(rs, msk, 64);
                    lrow[q2][i] = lrow[q2][i] * alpha + rs;
                    mrow[q2][i] = mnew;
#pragma unroll
                    for (int df = 0; df < 4; ++df) O[q2][df][i] *= alpha;
                }
#pragma unroll
                for (int kf = 0; kf < 2; ++kf)
#pragma unroll
                    for (int i = 0; i < 4; ++i)
                        Ps[w][q2 * 16 + g * 4 + i][kf * 16 + row] =
                            (__bf16)s[q2][kf][i];
            }
            // O += P @ V
#pragma unroll
            for (int q2 = 0; q2 < 2; ++q2) {
                bf16x8 pa = *(const bf16x8*)&Ps[w][q2 * 16 + row][g * 8];
#pragma unroll
                for (int df = 0; df < 4; ++df) {
                    bf16x8 vb = *(const bf16x8*)&Vs[df * 16 + row][g * 8];
                    O[q2][df] = MFMA16(pa, vb, O[q2][df]);
                }
            }
        }
    }

    const int b = bh >> 4, h = bh & 15;
#pragma unroll
    for (int q2 = 0; q2 < 2; ++q2)
#pragma unroll
        for (int df = 0; df < 4; ++df)
#pragma unroll
            for (int i = 0; i < 4; ++i) {
                int lq = qw + q2 * 16 + g * 4 + i;
                float val = O[q2][df][i] / lrow[q2][i];
                Yw[((size_t)(b * 2048 + lq)) * 1024 + h * 64 + df * 16 + row] =
                    (__bf16)val;
            }
}

// ---------------------------------------------------------------------------
// Proj GEMM: out[8192,1024] = Y[8192,1024](bf16) @ Wproj[1024,1024](fp32)
//            + bproj, fp32 out.
// ---------------------------------------------------------------------------
__global__ __launch_bounds__(256, 2)
void proj_gemm_kernel(const __bf16* __restrict__ Ya, const float* __restrict__ W,
                      const float* __restrict__ bias, float* __restrict__ out)
{
    __shared__ __bf16 As[128][40];
    __shared__ __bf16 Bs[128][40];
    const int tid = threadIdx.x;
    const int lane = tid & 63;
    const int w = tid >> 6;
    const int wr = w >> 1, wc = w & 1;
    const int row = lane & 15, g = lane >> 4;
    const int m0 = blockIdx.x * 128;
    const int n0 = blockIdx.y * 128;

    const f32x4 fzero = {0.f, 0.f, 0.f, 0.f};
    f32x4 acc[4][4];
#pragma unroll
    for (int a = 0; a < 4; ++a)
#pragma unroll
        for (int b = 0; b < 4; ++b) acc[a][b] = fzero;

    for (int k0 = 0; k0 < 1024; k0 += 32) {
        __syncthreads();
        // A: bf16 workspace, direct bf16x8 copy
#pragma unroll
        for (int i = 0; i < 2; ++i) {
            int lin = i * 256 + tid;
            int ar = lin >> 2, ac = (lin & 3) * 8;
            *(bf16x8*)&As[ar][ac] =
                *(const bf16x8*)&Ya[(size_t)(m0 + ar) * 1024 + k0 + ac];
        }
        // B: fp32 Wproj -> bf16, transposed
#pragma unroll
        for (int i = 0; i < 2; ++i) {
            int lin = i * 256 + tid;
            int bk = lin >> 4, bn = (lin & 15) * 8;
            const float* src = &W[(size_t)(k0 + bk) * 1024 + n0 + bn];
            f32x4 lo = *(const f32x4*)src;
            f32x4 hi = *(const f32x4*)(src + 4);
#pragma unroll
            for (int j = 0; j < 4; ++j) {
                Bs[bn + j][bk] = (__bf16)lo[j];
                Bs[bn + 4 + j][bk] = (__bf16)hi[j];
            }
        }
        __syncthreads();

        bf16x8 af[4], bfr[4];
#pragma unroll
        for (int mf = 0; mf < 4; ++mf)
            af[mf] = *(const bf16x8*)&As[wr * 64 + mf * 16 + row][g * 8];
#pragma unroll
        for (int nf = 0; nf < 4; ++nf)
            bfr[nf] = *(const bf16x8*)&Bs[wc * 64 + nf * 16 + row][g * 8];
#pragma unroll
        for (int mf = 0; mf < 4; ++mf)
#pragma unroll
            for (int nf = 0; nf < 4; ++nf)
                acc[mf][nf] = MFMA16(af[mf], bfr[nf], acc[mf][nf]);
    }

#pragma unroll
    for (int mf = 0; mf < 4; ++mf)
#pragma unroll
        for (int nf = 0; nf < 4; ++nf) {
            int n = n0 + wc * 64 + nf * 16 + row;
            float bv = bias[n];
#pragma unroll
            for (int i = 0; i < 4; ++i) {
                int mm = m0 + wr * 64 + mf * 16 + g * 4 + i;
                out[(size_t)mm * 1024 + n] = acc[mf][nf][i] + bv;
            }
        }
}

// ---------------------------------------------------------------------------
extern "C" void kernel_launch(void* const* d_in, const int* in_sizes, int n_in,
                              void* d_out, int out_size, void* d_ws, size_t ws_size,
                              hipStream_t stream)
{
    const float* x     = (const float*)d_in[0];
    const float* wqkv  = (const float*)d_in[1];
    const float* bqkv  = (const float*)d_in[2];
    const float* wproj = (const float*)d_in[3];
    const float* bproj = (const float*)d_in[4];
    float* out = (float*)d_out;

    const size_t elems = (size_t)4 * 16 * 2048 * 64;  // 8,388,608 per tensor
    __bf16* q = (__bf16*)d_ws;
    __bf16* k = q + elems;
    __bf16* v = k + elems;
    __bf16* y = v + elems;

    qkv_gemm_kernel<<<dim3(64, 24), 256, 0, stream>>>(x, wqkv, bqkv, q, k, v);
    attn_kernel<<<dim3(16, 64), 256, 0, stream>>>(q, k, v, y);
    proj_gemm_kernel<<<dim3(64, 8), 256, 0, stream>>>(y, wproj, bproj, out);
}

// Round 3
// 426.132 us; speedup vs baseline: 1.4999x; 1.4999x over previous
//
#include <hip/hip_runtime.h>

// B=4, L=2048, D=1024, H=16, HD=64.
// d_in fp32: x, Wqkv, bqkv, Wproj, bproj. d_out fp32.
// Pipeline: one-time fp32->bf16 conversion (X straight; W transposed to k-major),
// m97-style bf16 MFMA GEMMs with global_load_lds, barrier-free flash attention.

typedef __bf16 bf16x8 __attribute__((ext_vector_type(8)));
typedef float f32x4 __attribute__((ext_vector_type(4)));

#define MFMA16(a, b, c) __builtin_amdgcn_mfma_f32_16x16x32_bf16(a, b, c, 0, 0, 0)

__device__ __forceinline__ void gload_lds16(const __bf16* g, __bf16* l) {
    __builtin_amdgcn_global_load_lds(
        (const __attribute__((address_space(1))) void*)g,
        (__attribute__((address_space(3))) void*)l, 16, 0, 0);
}

// ---------------------------------------------------------------------------
// fp32 -> bf16 straight convert (n multiple of 2048)
// ---------------------------------------------------------------------------
__global__ void convert_kernel(const float* __restrict__ in, __bf16* __restrict__ out)
{
    int i = (blockIdx.x * 256 + threadIdx.x) * 8;
    f32x4 lo = *(const f32x4*)&in[i];
    f32x4 hi = *(const f32x4*)&in[i + 4];
    bf16x8 o;
#pragma unroll
    for (int j = 0; j < 4; ++j) { o[j] = (__bf16)lo[j]; o[j + 4] = (__bf16)hi[j]; }
    *(bf16x8*)&out[i] = o;
}

// ---------------------------------------------------------------------------
// fp32 [R][C] -> bf16 [C][R] transpose-convert. Grid (C/32, R/32), 256 thr.
// ---------------------------------------------------------------------------
__global__ void transpose_convert_kernel(const float* __restrict__ in,
                                         __bf16* __restrict__ out, int R, int C)
{
    __shared__ __bf16 t[32][33];
    const int c0 = blockIdx.x * 32, r0 = blockIdx.y * 32;
    const int tx = threadIdx.x & 31, ty = threadIdx.x >> 5;
#pragma unroll
    for (int j = 0; j < 4; ++j) {
        int r = ty + j * 8;
        t[tx][r] = (__bf16)in[(size_t)(r0 + r) * C + c0 + tx];
    }
    __syncthreads();
#pragma unroll
    for (int j = 0; j < 4; ++j) {
        int r = ty + j * 8;
        out[(size_t)(c0 + r) * R + r0 + tx] = t[r][tx];
    }
}

// ---------------------------------------------------------------------------
// m97-style GEMM core: C[m][n] = A[m][k] * Bt[n][k], 128x128 tile, BK=32,
// 4 waves (2x2). global_load_lds(16B) linear dest; source chunk pre-swizzled
// with s(r) = (r>>1)&3 and frag reads apply the same XOR (involution).
// ---------------------------------------------------------------------------
#define GEMM_TILE_LOOP(Abase, Bbase)                                               \
    for (int k0 = 0; k0 < 1024; k0 += 32) {                                        \
        __syncthreads();                                                           \
        _Pragma("unroll")                                                          \
        for (int i = 0; i < 2; ++i) {                                              \
            int wl = w * 2 + i;                                                    \
            int r = wl * 16 + (lane >> 2);                                         \
            int c = ((lane & 3) ^ ((r >> 1) & 3)) * 8;                             \
            gload_lds16(&Abase[(size_t)(m0 + r) * 1024 + k0 + c], &As[wl * 512]);  \
            gload_lds16(&Bbase[(size_t)(n0 + r) * 1024 + k0 + c], &Bs[wl * 512]);  \
        }                                                                          \
        __syncthreads();                                                           \
        bf16x8 af[4], bfr[4];                                                      \
        _Pragma("unroll")                                                          \
        for (int mf = 0; mf < 4; ++mf) {                                           \
            int rr = wr * 64 + mf * 16 + row;                                      \
            af[mf] = *(const bf16x8*)&As[rr * 32 + ((g ^ ((rr >> 1) & 3)) * 8)];   \
        }                                                                          \
        _Pragma("unroll")                                                          \
        for (int nf = 0; nf < 4; ++nf) {                                           \
            int rr = wc * 64 + nf * 16 + row;                                      \
            bfr[nf] = *(const bf16x8*)&Bs[rr * 32 + ((g ^ ((rr >> 1) & 3)) * 8)];  \
        }                                                                          \
        _Pragma("unroll")                                                          \
        for (int mf = 0; mf < 4; ++mf)                                             \
            _Pragma("unroll")                                                      \
            for (int nf = 0; nf < 4; ++nf)                                         \
                acc[mf][nf] = MFMA16(af[mf], bfr[nf], acc[mf][nf]);                \
    }

// QKV: A=xb[8192][1024], Bt=wqkvT[3072][1024]. q,k -> [B,H,L,64]; v -> [B,H,64,L].
__global__ __launch_bounds__(256, 2)
void qkv_gemm_kernel(const __bf16* __restrict__ A, const __bf16* __restrict__ Bt,
                     const float* __restrict__ bias,
                     __bf16* __restrict__ qo, __bf16* __restrict__ ko,
                     __bf16* __restrict__ vt)
{
    __shared__ __bf16 As[128 * 32];
    __shared__ __bf16 Bs[128 * 32];
    const int tid = threadIdx.x;
    const int lane = tid & 63;
    const int w = tid >> 6;
    const int wr = w >> 1, wc = w & 1;
    const int row = lane & 15, g = lane >> 4;
    const int m0 = blockIdx.x * 128;
    const int n0 = blockIdx.y * 128;

    const f32x4 fzero = {0.f, 0.f, 0.f, 0.f};
    f32x4 acc[4][4];
#pragma unroll
    for (int a = 0; a < 4; ++a)
#pragma unroll
        for (int b = 0; b < 4; ++b) acc[a][b] = fzero;

    GEMM_TILE_LOOP(A, Bt)

#pragma unroll
    for (int mf = 0; mf < 4; ++mf)
#pragma unroll
        for (int nf = 0; nf < 4; ++nf) {
            int n = n0 + wc * 64 + nf * 16 + row;
            int part = n >> 10;  // 0=q 1=k 2=v (uniform per block)
            int d = n & 1023;
            int h = d >> 6, hd = d & 63;
            float bv = bias[n];
#pragma unroll
            for (int i = 0; i < 4; ++i) {
                int mm = m0 + wr * 64 + mf * 16 + g * 4 + i;
                int b = mm >> 11, l = mm & 2047;
                __bf16 val = (__bf16)(acc[mf][nf][i] + bv);
                if (part == 0)
                    qo[(((size_t)(b * 16 + h) * 2048) + l) * 64 + hd] = val;
                else if (part == 1)
                    ko[(((size_t)(b * 16 + h) * 2048) + l) * 64 + hd] = val;
                else
                    vt[(((size_t)(b * 16 + h) * 64) + hd) * 2048 + l] = val;
            }
        }
}

// Proj: A=y[8192][1024](bf16), Bt=wprojT[1024][1024](bf16), fp32 out + bias.
__global__ __launch_bounds__(256, 2)
void proj_gemm_kernel(const __bf16* __restrict__ A, const __bf16* __restrict__ Bt,
                      const float* __restrict__ bias, float* __restrict__ out)
{
    __shared__ __bf16 As[128 * 32];
    __shared__ __bf16 Bs[128 * 32];
    const int tid = threadIdx.x;
    const int lane = tid & 63;
    const int w = tid >> 6;
    const int wr = w >> 1, wc = w & 1;
    const int row = lane & 15, g = lane >> 4;
    const int m0 = blockIdx.x * 128;
    const int n0 = blockIdx.y * 128;

    const f32x4 fzero = {0.f, 0.f, 0.f, 0.f};
    f32x4 acc[4][4];
#pragma unroll
    for (int a = 0; a < 4; ++a)
#pragma unroll
        for (int b = 0; b < 4; ++b) acc[a][b] = fzero;

    GEMM_TILE_LOOP(A, Bt)

#pragma unroll
    for (int mf = 0; mf < 4; ++mf)
#pragma unroll
        for (int nf = 0; nf < 4; ++nf) {
            int n = n0 + wc * 64 + nf * 16 + row;
            float bv = bias[n];
#pragma unroll
            for (int i = 0; i < 4; ++i) {
                int mm = m0 + wr * 64 + mf * 16 + g * 4 + i;
                out[(size_t)mm * 1024 + n] = acc[mf][nf][i] + bv;
            }
        }
}

// ---------------------------------------------------------------------------
// Barrier-free causal flash attention. Grid (16, B*H=64), 256 thr = 4 waves.
// Wave w owns q rows [qbase+32w, +32). KVBLK=64. K direct from global,
// V^T direct from global ([B,H,64,L] workspace); only per-wave P LDS repack.
// ---------------------------------------------------------------------------
__global__ __launch_bounds__(256, 3)
void attn_kernel(const __bf16* __restrict__ Qw, const __bf16* __restrict__ Kw,
                 const __bf16* __restrict__ Vt, __bf16* __restrict__ Yw)
{
    __shared__ __bf16 Ps[4][32][72];   // per-wave [q][k], pad 64->72
    const int tid = threadIdx.x;
    const int lane = tid & 63;
    const int w = tid >> 6;
    const int row = lane & 15, g = lane >> 4;
    const int bh = blockIdx.y;
    const int qbase = (gridDim.x - 1 - blockIdx.x) * 128;  // long blocks first
    const int qw = qbase + w * 32;
    const __bf16* Q = Qw + (size_t)bh * 2048 * 64;
    const __bf16* K = Kw + (size_t)bh * 2048 * 64;
    const __bf16* V = Vt + (size_t)bh * 64 * 2048;   // [64 d][2048 k]

    bf16x8 qf[2][2];
#pragma unroll
    for (int q2 = 0; q2 < 2; ++q2)
#pragma unroll
        for (int dc = 0; dc < 2; ++dc)
            qf[q2][dc] = *(const bf16x8*)
                &Q[(size_t)(qw + q2 * 16 + row) * 64 + dc * 32 + g * 8];

    const f32x4 fzero = {0.f, 0.f, 0.f, 0.f};
    f32x4 O[2][4];
    float mrow[2][4], lrow[2][4];
#pragma unroll
    for (int q2 = 0; q2 < 2; ++q2) {
#pragma unroll
        for (int df = 0; df < 4; ++df) O[q2][df] = fzero;
#pragma unroll
        for (int i = 0; i < 4; ++i) {
            mrow[q2][i] = -__builtin_inff();
            lrow[q2][i] = 0.f;
        }
    }

    for (int kb = 0; kb <= qw + 31; kb += 64) {
        // ---- S = Q K^T over up to 64 keys
        f32x4 s[2][4];
#pragma unroll
        for (int q2 = 0; q2 < 2; ++q2)
#pragma unroll
            for (int kf = 0; kf < 4; ++kf) s[q2][kf] = fzero;
#pragma unroll
        for (int kf = 0; kf < 4; ++kf) {
            if (kb + kf * 16 <= qw + 31) {   // wave-uniform tail skip
                bf16x8 kfr[2];
#pragma unroll
                for (int dc = 0; dc < 2; ++dc)
                    kfr[dc] = *(const bf16x8*)
                        &K[(size_t)(kb + kf * 16 + row) * 64 + dc * 32 + g * 8];
#pragma unroll
                for (int q2 = 0; q2 < 2; ++q2)
#pragma unroll
                    for (int dc = 0; dc < 2; ++dc)
                        s[q2][kf] = MFMA16(qf[q2][dc], kfr[dc], s[q2][kf]);
            }
        }
        // ---- online softmax (row lives across the 16-lane group)
#pragma unroll
        for (int q2 = 0; q2 < 2; ++q2) {
#pragma unroll
            for (int i = 0; i < 4; ++i) {
                int qg = qw + q2 * 16 + g * 4 + i;
                float t = -1e30f;
#pragma unroll
                for (int kf = 0; kf < 4; ++kf) {
                    int kg = kb + kf * 16 + row;
                    float sv = s[q2][kf][i] * 0.125f;
                    sv = (kg > qg) ? -1e30f : sv;
                    s[q2][kf][i] = sv;
                    t = fmaxf(t, sv);
                }
#pragma unroll
                for (int msk = 1; msk <= 8; msk <<= 1)
                    t = fmaxf(t, __shfl_xor(t, msk, 64));
                float mnew = fmaxf(mrow[q2][i], t);
                float alpha = __expf(mrow[q2][i] - mnew);
                float rs = 0.f;
#pragma unroll
                for (int kf = 0; kf < 4; ++kf) {
                    float p = __expf(s[q2][kf][i] - mnew);
                    s[q2][kf][i] = p;
                    rs += p;
                }
#pragma unroll
                for (int msk = 1; msk <= 8; msk <<= 1)
                    rs += __shfl_xor(rs, msk, 64);
                lrow[q2][i] = lrow[q2][i] * alpha + rs;
                mrow[q2][i] = mnew;
#pragma unroll
                for (int df = 0; df < 4; ++df) O[q2][df][i] *= alpha;
            }
            // spill P (C-layout) to per-wave LDS for A-layout reload
#pragma unroll
            for (int kf = 0; kf < 4; ++kf)
#pragma unroll
                for (int i = 0; i < 4; ++i)
                    Ps[w][q2 * 16 + g * 4 + i][kf * 16 + row] =
                        (__bf16)s[q2][kf][i];
        }
        // ---- O += P V  (V^T streamed from global)
#pragma unroll
        for (int ks = 0; ks < 2; ++ks) {
            if (kb + ks * 32 <= qw + 31) {   // wave-uniform, also bounds V reads
#pragma unroll
                for (int q2 = 0; q2 < 2; ++q2) {
                    bf16x8 pa = *(const bf16x8*)&Ps[w][q2 * 16 + row][ks * 32 + g * 8];
#pragma unroll
                    for (int df = 0; df < 4; ++df) {
                        bf16x8 vb = *(const bf16x8*)
                            &V[(size_t)(df * 16 + row) * 2048 + kb + ks * 32 + g * 8];
                        O[q2][df] = MFMA16(pa, vb, O[q2][df]);
                    }
                }
            }
        }
    }

    const int b = bh >> 4, h = bh & 15;
#pragma unroll
    for (int q2 = 0; q2 < 2; ++q2)
#pragma unroll
        for (int df = 0; df < 4; ++df)
#pragma unroll
            for (int i = 0; i < 4; ++i) {
                int lq = qw + q2 * 16 + g * 4 + i;
                float val = O[q2][df][i] / lrow[q2][i];
                Yw[((size_t)(b * 2048 + lq)) * 1024 + h * 64 + df * 16 + row] =
                    (__bf16)val;
            }
}

// ---------------------------------------------------------------------------
extern "C" void kernel_launch(void* const* d_in, const int* in_sizes, int n_in,
                              void* d_out, int out_size, void* d_ws, size_t ws_size,
                              hipStream_t stream)
{
    const float* x     = (const float*)d_in[0];
    const float* wqkv  = (const float*)d_in[1];
    const float* bqkv  = (const float*)d_in[2];
    const float* wproj = (const float*)d_in[3];
    const float* bproj = (const float*)d_in[4];
    float* out = (float*)d_out;

    const size_t E = (size_t)4 * 16 * 2048 * 64;  // 8,388,608 per [B,H,L,64] tensor
    __bf16* q      = (__bf16*)d_ws;               // E
    __bf16* k      = q + E;                       // E
    __bf16* vt     = k + E;                       // E ([B,H,64,L])
    __bf16* xb     = vt + E;                      // E  (x bf16)
    __bf16* y      = xb;                          // alias: y written after xb consumed
    __bf16* wqkvT  = xb + E;                      // 3072*1024
    __bf16* wprojT = wqkvT + (size_t)3072 * 1024; // 1024*1024

    convert_kernel<<<4096, 256, 0, stream>>>(x, xb);
    transpose_convert_kernel<<<dim3(96, 32), 256, 0, stream>>>(wqkv, wqkvT, 1024, 3072);
    transpose_convert_kernel<<<dim3(32, 32), 256, 0, stream>>>(wproj, wprojT, 1024, 1024);
    qkv_gemm_kernel<<<dim3(64, 24), 256, 0, stream>>>(xb, wqkvT, bqkv, q, k, vt);
    attn_kernel<<<dim3(16, 64), 256, 0, stream>>>(q, k, vt, y);
    proj_gemm_kernel<<<dim3(64, 8), 256, 0, stream>>>(y, wprojT, bproj, out);
}

// Round 5
// 362.365 us; speedup vs baseline: 1.7638x; 1.1760x over previous
//
#include <hip/hip_runtime.h>

// B=4, L=2048, D=1024, H=16, HD=64.
// d_in fp32: x, Wqkv, bqkv, Wproj, bproj. d_out fp32.
// Pipeline: one-time fp32->bf16 conversion (X straight; W transposed k-major),
// m97-style bf16 MFMA GEMMs with global_load_lds, and swapped-operand
// LDS-free causal flash attention with in-register softmax (shfl_xor based).

typedef __bf16 bf16x8 __attribute__((ext_vector_type(8)));
typedef float f32x4 __attribute__((ext_vector_type(4)));
typedef float f32x16 __attribute__((ext_vector_type(16)));
typedef unsigned u32x4 __attribute__((ext_vector_type(4)));

#define MFMA16(a, b, c) __builtin_amdgcn_mfma_f32_16x16x32_bf16(a, b, c, 0, 0, 0)
#define MFMA32(a, b, c) __builtin_amdgcn_mfma_f32_32x32x16_bf16(a, b, c, 0, 0, 0)

__device__ __forceinline__ void gload_lds16(const __bf16* g, __bf16* l) {
    __builtin_amdgcn_global_load_lds(
        (const __attribute__((address_space(1))) void*)g,
        (__attribute__((address_space(3))) void*)l, 16, 0, 0);
}

__device__ __forceinline__ unsigned pkbf(float a, float b) {
    unsigned short ua = __builtin_bit_cast(unsigned short, (__bf16)a);
    unsigned short ub = __builtin_bit_cast(unsigned short, (__bf16)b);
    return (unsigned)ua | ((unsigned)ub << 16);
}

// ---------------------------------------------------------------------------
// fp32 -> bf16 straight convert (n multiple of 2048)
// ---------------------------------------------------------------------------
__global__ void convert_kernel(const float* __restrict__ in, __bf16* __restrict__ out)
{
    int i = (blockIdx.x * 256 + threadIdx.x) * 8;
    f32x4 lo = *(const f32x4*)&in[i];
    f32x4 hi = *(const f32x4*)&in[i + 4];
    bf16x8 o;
#pragma unroll
    for (int j = 0; j < 4; ++j) { o[j] = (__bf16)lo[j]; o[j + 4] = (__bf16)hi[j]; }
    *(bf16x8*)&out[i] = o;
}

// ---------------------------------------------------------------------------
// fp32 [R][C] -> bf16 [C][R] transpose-convert. Grid (C/32, R/32), 256 thr.
// ---------------------------------------------------------------------------
__global__ void transpose_convert_kernel(const float* __restrict__ in,
                                         __bf16* __restrict__ out, int R, int C)
{
    __shared__ __bf16 t[32][33];
    const int c0 = blockIdx.x * 32, r0 = blockIdx.y * 32;
    const int tx = threadIdx.x & 31, ty = threadIdx.x >> 5;
#pragma unroll
    for (int j = 0; j < 4; ++j) {
        int r = ty + j * 8;
        t[tx][r] = (__bf16)in[(size_t)(r0 + r) * C + c0 + tx];
    }
    __syncthreads();
#pragma unroll
    for (int j = 0; j < 4; ++j) {
        int r = ty + j * 8;
        out[(size_t)(c0 + r) * R + r0 + tx] = t[r][tx];
    }
}

// ---------------------------------------------------------------------------
// m97-style GEMM core: C[m][n] = A[m][k] * Bt[n][k], 128x128 tile, BK=32,
// 4 waves (2x2). global_load_lds(16B) linear dest; source chunk pre-swizzled
// with s(r) = (r>>1)&3 and frag reads apply the same XOR (involution).
// ---------------------------------------------------------------------------
#define GEMM_TILE_LOOP(Abase, Bbase)                                               \
    for (int k0 = 0; k0 < 1024; k0 += 32) {                                        \
        __syncthreads();                                                           \
        _Pragma("unroll")                                                          \
        for (int i = 0; i < 2; ++i) {                                              \
            int wl = w * 2 + i;                                                    \
            int r = wl * 16 + (lane >> 2);                                         \
            int c = ((lane & 3) ^ ((r >> 1) & 3)) * 8;                             \
            gload_lds16(&Abase[(size_t)(m0 + r) * 1024 + k0 + c], &As[wl * 512]);  \
            gload_lds16(&Bbase[(size_t)(n0 + r) * 1024 + k0 + c], &Bs[wl * 512]);  \
        }                                                                          \
        __syncthreads();                                                           \
        bf16x8 af[4], bfr[4];                                                      \
        _Pragma("unroll")                                                          \
        for (int mf = 0; mf < 4; ++mf) {                                           \
            int rr = wr * 64 + mf * 16 + row;                                      \
            af[mf] = *(const bf16x8*)&As[rr * 32 + ((g ^ ((rr >> 1) & 3)) * 8)];   \
        }                                                                          \
        _Pragma("unroll")                                                          \
        for (int nf = 0; nf < 4; ++nf) {                                           \
            int rr = wc * 64 + nf * 16 + row;                                      \
            bfr[nf] = *(const bf16x8*)&Bs[rr * 32 + ((g ^ ((rr >> 1) & 3)) * 8)];  \
        }                                                                          \
        _Pragma("unroll")                                                          \
        for (int mf = 0; mf < 4; ++mf)                                             \
            _Pragma("unroll")                                                      \
            for (int nf = 0; nf < 4; ++nf)                                         \
                acc[mf][nf] = MFMA16(af[mf], bfr[nf], acc[mf][nf]);                \
    }

// QKV: A=xb[8192][1024], Bt=wqkvT[3072][1024]. q,k -> [B,H,L,64]; v -> [B,H,64,L].
__global__ __launch_bounds__(256, 2)
void qkv_gemm_kernel(const __bf16* __restrict__ A, const __bf16* __restrict__ Bt,
                     const float* __restrict__ bias,
                     __bf16* __restrict__ qo, __bf16* __restrict__ ko,
                     __bf16* __restrict__ vt)
{
    __shared__ __bf16 As[128 * 32];
    __shared__ __bf16 Bs[128 * 32];
    const int tid = threadIdx.x;
    const int lane = tid & 63;
    const int w = tid >> 6;
    const int wr = w >> 1, wc = w & 1;
    const int row = lane & 15, g = lane >> 4;
    const int m0 = blockIdx.x * 128;
    const int n0 = blockIdx.y * 128;

    const f32x4 fzero = {0.f, 0.f, 0.f, 0.f};
    f32x4 acc[4][4];
#pragma unroll
    for (int a = 0; a < 4; ++a)
#pragma unroll
        for (int b = 0; b < 4; ++b) acc[a][b] = fzero;

    GEMM_TILE_LOOP(A, Bt)

#pragma unroll
    for (int mf = 0; mf < 4; ++mf)
#pragma unroll
        for (int nf = 0; nf < 4; ++nf) {
            int n = n0 + wc * 64 + nf * 16 + row;
            int part = n >> 10;  // 0=q 1=k 2=v (uniform per block)
            int d = n & 1023;
            int h = d >> 6, hd = d & 63;
            float bv = bias[n];
#pragma unroll
            for (int i = 0; i < 4; ++i) {
                int mm = m0 + wr * 64 + mf * 16 + g * 4 + i;
                int b = mm >> 11, l = mm & 2047;
                __bf16 val = (__bf16)(acc[mf][nf][i] + bv);
                if (part == 0)
                    qo[(((size_t)(b * 16 + h) * 2048) + l) * 64 + hd] = val;
                else if (part == 1)
                    ko[(((size_t)(b * 16 + h) * 2048) + l) * 64 + hd] = val;
                else
                    vt[(((size_t)(b * 16 + h) * 64) + hd) * 2048 + l] = val;
            }
        }
}

// Proj: A=y[8192][1024](bf16), Bt=wprojT[1024][1024](bf16), fp32 out + bias.
__global__ __launch_bounds__(256, 2)
void proj_gemm_kernel(const __bf16* __restrict__ A, const __bf16* __restrict__ Bt,
                      const float* __restrict__ bias, float* __restrict__ out)
{
    __shared__ __bf16 As[128 * 32];
    __shared__ __bf16 Bs[128 * 32];
    const int tid = threadIdx.x;
    const int lane = tid & 63;
    const int w = tid >> 6;
    const int wr = w >> 1, wc = w & 1;
    const int row = lane & 15, g = lane >> 4;
    const int m0 = blockIdx.x * 128;
    const int n0 = blockIdx.y * 128;

    const f32x4 fzero = {0.f, 0.f, 0.f, 0.f};
    f32x4 acc[4][4];
#pragma unroll
    for (int a = 0; a < 4; ++a)
#pragma unroll
        for (int b = 0; b < 4; ++b) acc[a][b] = fzero;

    GEMM_TILE_LOOP(A, Bt)

#pragma unroll
    for (int mf = 0; mf < 4; ++mf)
#pragma unroll
        for (int nf = 0; nf < 4; ++nf) {
            int n = n0 + wc * 64 + nf * 16 + row;
            float bv = bias[n];
#pragma unroll
            for (int i = 0; i < 4; ++i) {
                int mm = m0 + wr * 64 + mf * 16 + g * 4 + i;
                out[(size_t)mm * 1024 + n] = acc[mf][nf][i] + bv;
            }
        }
}

// ---------------------------------------------------------------------------
// LDS-free swapped-operand causal flash attention.
// Grid (32, B*H=64), 128 thr = 2 waves; wave wv owns q rows [qt+32wv, +32).
// S^T = mfma32(K, Q): lane owns q-col = lane&31, 16 k-values in-register
// (k = (r&3)+8*(r>>2)+4*hi); partner lane (l^32) holds the other 16.
// O^T = mfma32(V^T, P^T): same q-col per lane -> m/l/alpha all lane-local.
// All cross-lane movement via __shfl_xor(.,32) (unambiguous semantics).
// ---------------------------------------------------------------------------
__global__ __launch_bounds__(128, 4)
void attn_kernel(const __bf16* __restrict__ Qw, const __bf16* __restrict__ Kw,
                 const __bf16* __restrict__ Vt, __bf16* __restrict__ Yw)
{
    const int tid = threadIdx.x;
    const int lane = tid & 63;
    const int wv = tid >> 6;
    const int col = lane & 31;          // q owned by this lane
    const int hi = lane >> 5;
    const int bh = blockIdx.y;
    const int qt = (gridDim.x - 1 - blockIdx.x) * 64;  // long blocks first
    const int qw = qt + wv * 32;
    const __bf16* Q = Qw + (size_t)bh * 2048 * 64;
    const __bf16* K = Kw + (size_t)bh * 2048 * 64;
    const __bf16* V = Vt + (size_t)bh * 64 * 2048;   // [64 d][2048 k]

    // Q B-frags: lane supplies Q[qw+col][dc*16 + hi*8 + j]
    bf16x8 qf[4];
#pragma unroll
    for (int dc = 0; dc < 4; ++dc)
        qf[dc] = *(const bf16x8*)&Q[(size_t)(qw + col) * 64 + dc * 16 + hi * 8];

    f32x16 Ot[2];
#pragma unroll
    for (int dt = 0; dt < 2; ++dt)
#pragma unroll
        for (int i = 0; i < 16; ++i) Ot[dt][i] = 0.f;
    float m = -__builtin_inff(), lsum = 0.f;
    const float cexp = 0.18033688f;     // 0.125 * log2(e)

    for (int kb = 0; kb <= qw; kb += 32) {
        // ---- S^T tile: C[k][q], k = (r&3)+8*(r>>2)+4*hi, q = col
        f32x16 st;
#pragma unroll
        for (int i = 0; i < 16; ++i) st[i] = 0.f;
#pragma unroll
        for (int dc = 0; dc < 4; ++dc) {
            bf16x8 kf = *(const bf16x8*)&K[(size_t)(kb + col) * 64 + dc * 16 + hi * 8];
            st = MFMA32(kf, qf[dc], st);
        }
        // ---- diagonal mask (only the last tile touches the diagonal)
        if (kb == qw) {
#pragma unroll
            for (int r = 0; r < 16; ++r) {
                int crow = (r & 3) + 8 * (r >> 2) + 4 * hi;
                if (crow > col) st[r] = -1e30f;
            }
        }
        // ---- in-lane max + one cross-half reduce
        float pmax = st[0];
#pragma unroll
        for (int r = 1; r < 16; ++r) pmax = fmaxf(pmax, st[r]);
        pmax = fmaxf(pmax, __shfl_xor(pmax, 32, 64));
        // ---- defer-max (T13): rescale only when max grows materially
        if (!__all(pmax - m <= 44.0f)) {
            float mnew = fmaxf(m, pmax);
            float alpha = exp2f((m - mnew) * cexp);
#pragma unroll
            for (int dt = 0; dt < 2; ++dt)
#pragma unroll
                for (int i = 0; i < 16; ++i) Ot[dt][i] *= alpha;
            lsum *= alpha;
            m = mnew;
        }
        // ---- p = 2^((s-m)*c), in-lane sum + one cross-half reduce
        float rs = 0.f;
#pragma unroll
        for (int r = 0; r < 16; ++r) {
            float p = exp2f((st[r] - m) * cexp);
            st[r] = p;
            rs += p;
        }
        rs += __shfl_xor(rs, 32, 64);
        lsum += rs;
        // ---- pack P^T -> B-frags. Own words u0..u7 (consecutive k pairs);
        // partner's via shfl_xor 32. Target: pa element j = P[col][kb+ph*8+j]
        // (ph = hi for pa0 halves handled by select below).
        unsigned u0 = pkbf(st[0], st[1]),   u1 = pkbf(st[2], st[3]);
        unsigned u2 = pkbf(st[4], st[5]),   u3 = pkbf(st[6], st[7]);
        unsigned u4 = pkbf(st[8], st[9]),   u5 = pkbf(st[10], st[11]);
        unsigned u6 = pkbf(st[12], st[13]), u7 = pkbf(st[14], st[15]);
        unsigned xu0 = __shfl_xor((int)u0, 32, 64), xu1 = __shfl_xor((int)u1, 32, 64);
        unsigned xu2 = __shfl_xor((int)u2, 32, 64), xu3 = __shfl_xor((int)u3, 32, 64);
        unsigned xu4 = __shfl_xor((int)u4, 32, 64), xu5 = __shfl_xor((int)u5, 32, 64);
        unsigned xu6 = __shfl_xor((int)u6, 32, 64), xu7 = __shfl_xor((int)u7, 32, 64);
        // hi=0 owns k{0..3,8..11,16..19,24..27}; hi=1 owns k{4..7,...}.
        u32x4 w0 = {hi ? xu2 : u0, hi ? xu3 : u1, hi ? u2 : xu0, hi ? u3 : xu1};
        u32x4 w1 = {hi ? xu6 : u4, hi ? xu7 : u5, hi ? u6 : xu4, hi ? u7 : xu5};
        bf16x8 pa0 = __builtin_bit_cast(bf16x8, w0);   // P[q][kb+hi*8 .. +7]    (kk 0-15)
        bf16x8 pa1 = __builtin_bit_cast(bf16x8, w1);   // P[q][kb+16+hi*8 .. +7] (kk 16-31)
        // ---- O^T += V^T P^T
#pragma unroll
        for (int dt = 0; dt < 2; ++dt) {
            bf16x8 v0 = *(const bf16x8*)&V[(size_t)(dt * 32 + col) * 2048 + kb + hi * 8];
            Ot[dt] = MFMA32(v0, pa0, Ot[dt]);
            bf16x8 v1 = *(const bf16x8*)&V[(size_t)(dt * 32 + col) * 2048 + kb + 16 + hi * 8];
            Ot[dt] = MFMA32(v1, pa1, Ot[dt]);
        }
    }

    // ---- epilogue: O^T C-layout col=q(lane-local), d = dt*32+8*(r>>2)+4*hi+(r&3)
    const int b = bh >> 4, h = bh & 15;
    const float inv = 1.f / lsum;
    __bf16* yrow = Yw + ((size_t)(b * 2048 + qw + col)) * 1024 + h * 64;
#pragma unroll
    for (int dt = 0; dt < 2; ++dt)
#pragma unroll
        for (int rg = 0; rg < 4; ++rg) {
            int d0 = dt * 32 + rg * 8 + hi * 4;
            unsigned lo = pkbf(Ot[dt][rg * 4 + 0] * inv, Ot[dt][rg * 4 + 1] * inv);
            unsigned hi2 = pkbf(Ot[dt][rg * 4 + 2] * inv, Ot[dt][rg * 4 + 3] * inv);
            unsigned long long pk =
                (unsigned long long)lo | ((unsigned long long)hi2 << 32);
            *(unsigned long long*)&yrow[d0] = pk;
        }
}

// ---------------------------------------------------------------------------
extern "C" void kernel_launch(void* const* d_in, const int* in_sizes, int n_in,
                              void* d_out, int out_size, void* d_ws, size_t ws_size,
                              hipStream_t stream)
{
    const float* x     = (const float*)d_in[0];
    const float* wqkv  = (const float*)d_in[1];
    const float* bqkv  = (const float*)d_in[2];
    const float* wproj = (const float*)d_in[3];
    const float* bproj = (const float*)d_in[4];
    float* out = (float*)d_out;

    const size_t E = (size_t)4 * 16 * 2048 * 64;  // 8,388,608 per [B,H,L,64] tensor
    __bf16* q      = (__bf16*)d_ws;               // E
    __bf16* k      = q + E;                       // E
    __bf16* vt     = k + E;                       // E ([B,H,64,L])
    __bf16* xb     = vt + E;                      // E  (x bf16)
    __bf16* y      = xb;                          // alias: y written after xb consumed
    __bf16* wqkvT  = xb + E;                      // 3072*1024
    __bf16* wprojT = wqkvT + (size_t)3072 * 1024; // 1024*1024

    convert_kernel<<<4096, 256, 0, stream>>>(x, xb);
    transpose_convert_kernel<<<dim3(96, 32), 256, 0, stream>>>(wqkv, wqkvT, 1024, 3072);
    transpose_convert_kernel<<<dim3(32, 32), 256, 0, stream>>>(wproj, wprojT, 1024, 1024);
    qkv_gemm_kernel<<<dim3(64, 24), 256, 0, stream>>>(xb, wqkvT, bqkv, q, k, vt);
    attn_kernel<<<dim3(32, 64), 128, 0, stream>>>(q, k, vt, y);
    proj_gemm_kernel<<<dim3(64, 8), 256, 0, stream>>>(y, wprojT, bproj, out);
}

// Round 6
// 248.502 us; speedup vs baseline: 2.5720x; 1.4582x over previous
//
#include <hip/hip_runtime.h>

// B=4, L=2048, D=1024, H=16, HD=64.
// d_in fp32: x, Wqkv, bqkv, Wproj, bproj. d_out fp32.
// Pipeline: one-time fp32->bf16 conversion (X straight; W transposed k-major),
// m97-style bf16 MFMA GEMMs with global_load_lds, and swapped-operand LDS-free
// causal flash attention, anti-diagonal pair-balanced (q-tiles t and 63-t per
// wave), softmax scale pre-folded into Q.

typedef __bf16 bf16x8 __attribute__((ext_vector_type(8)));
typedef float f32x4 __attribute__((ext_vector_type(4)));
typedef float f32x16 __attribute__((ext_vector_type(16)));
typedef unsigned u32x4 __attribute__((ext_vector_type(4)));

#define MFMA16(a, b, c) __builtin_amdgcn_mfma_f32_16x16x32_bf16(a, b, c, 0, 0, 0)
#define MFMA32(a, b, c) __builtin_amdgcn_mfma_f32_32x32x16_bf16(a, b, c, 0, 0, 0)

__device__ __forceinline__ void gload_lds16(const __bf16* g, __bf16* l) {
    __builtin_amdgcn_global_load_lds(
        (const __attribute__((address_space(1))) void*)g,
        (__attribute__((address_space(3))) void*)l, 16, 0, 0);
}

__device__ __forceinline__ unsigned pkbf(float a, float b) {
    unsigned short ua = __builtin_bit_cast(unsigned short, (__bf16)a);
    unsigned short ub = __builtin_bit_cast(unsigned short, (__bf16)b);
    return (unsigned)ua | ((unsigned)ub << 16);
}

// ---------------------------------------------------------------------------
// fp32 -> bf16 straight convert (n multiple of 2048)
// ---------------------------------------------------------------------------
__global__ void convert_kernel(const float* __restrict__ in, __bf16* __restrict__ out)
{
    int i = (blockIdx.x * 256 + threadIdx.x) * 8;
    f32x4 lo = *(const f32x4*)&in[i];
    f32x4 hi = *(const f32x4*)&in[i + 4];
    bf16x8 o;
#pragma unroll
    for (int j = 0; j < 4; ++j) { o[j] = (__bf16)lo[j]; o[j + 4] = (__bf16)hi[j]; }
    *(bf16x8*)&out[i] = o;
}

// ---------------------------------------------------------------------------
// fp32 [R][C] -> bf16 [C][R] transpose-convert. Grid (C/32, R/32), 256 thr.
// ---------------------------------------------------------------------------
__global__ void transpose_convert_kernel(const float* __restrict__ in,
                                         __bf16* __restrict__ out, int R, int C)
{
    __shared__ __bf16 t[32][33];
    const int c0 = blockIdx.x * 32, r0 = blockIdx.y * 32;
    const int tx = threadIdx.x & 31, ty = threadIdx.x >> 5;
#pragma unroll
    for (int j = 0; j < 4; ++j) {
        int r = ty + j * 8;
        t[tx][r] = (__bf16)in[(size_t)(r0 + r) * C + c0 + tx];
    }
    __syncthreads();
#pragma unroll
    for (int j = 0; j < 4; ++j) {
        int r = ty + j * 8;
        out[(size_t)(c0 + r) * R + r0 + tx] = t[r][tx];
    }
}

// ---------------------------------------------------------------------------
// m97-style GEMM core: C[m][n] = A[m][k] * Bt[n][k], 128x128 tile, BK=32,
// 4 waves (2x2). global_load_lds(16B) linear dest; source chunk pre-swizzled
// with s(r) = (r>>1)&3 and frag reads apply the same XOR (involution).
// ---------------------------------------------------------------------------
#define GEMM_TILE_LOOP(Abase, Bbase)                                               \
    for (int k0 = 0; k0 < 1024; k0 += 32) {                                        \
        __syncthreads();                                                           \
        _Pragma("unroll")                                                          \
        for (int i = 0; i < 2; ++i) {                                              \
            int wl = w * 2 + i;                                                    \
            int r = wl * 16 + (lane >> 2);                                         \
            int c = ((lane & 3) ^ ((r >> 1) & 3)) * 8;                             \
            gload_lds16(&Abase[(size_t)(m0 + r) * 1024 + k0 + c], &As[wl * 512]);  \
            gload_lds16(&Bbase[(size_t)(n0 + r) * 1024 + k0 + c], &Bs[wl * 512]);  \
        }                                                                          \
        __syncthreads();                                                           \
        bf16x8 af[4], bfr[4];                                                      \
        _Pragma("unroll")                                                          \
        for (int mf = 0; mf < 4; ++mf) {                                           \
            int rr = wr * 64 + mf * 16 + row;                                      \
            af[mf] = *(const bf16x8*)&As[rr * 32 + ((g ^ ((rr >> 1) & 3)) * 8)];   \
        }                                                                          \
        _Pragma("unroll")                                                          \
        for (int nf = 0; nf < 4; ++nf) {                                           \
            int rr = wc * 64 + nf * 16 + row;                                      \
            bfr[nf] = *(const bf16x8*)&Bs[rr * 32 + ((g ^ ((rr >> 1) & 3)) * 8)];  \
        }                                                                          \
        _Pragma("unroll")                                                          \
        for (int mf = 0; mf < 4; ++mf)                                             \
            _Pragma("unroll")                                                      \
            for (int nf = 0; nf < 4; ++nf)                                         \
                acc[mf][nf] = MFMA16(af[mf], bfr[nf], acc[mf][nf]);                \
    }

// QKV: A=xb[8192][1024], Bt=wqkvT[3072][1024]. q(SCALED),k -> [B,H,L,64];
// v -> [B,H,64,L].
__global__ __launch_bounds__(256, 2)
void qkv_gemm_kernel(const __bf16* __restrict__ A, const __bf16* __restrict__ Bt,
                     const float* __restrict__ bias,
                     __bf16* __restrict__ qo, __bf16* __restrict__ ko,
                     __bf16* __restrict__ vt)
{
    __shared__ __bf16 As[128 * 32];
    __shared__ __bf16 Bs[128 * 32];
    const int tid = threadIdx.x;
    const int lane = tid & 63;
    const int w = tid >> 6;
    const int wr = w >> 1, wc = w & 1;
    const int row = lane & 15, g = lane >> 4;
    const int m0 = blockIdx.x * 128;
    const int n0 = blockIdx.y * 128;

    const f32x4 fzero = {0.f, 0.f, 0.f, 0.f};
    f32x4 acc[4][4];
#pragma unroll
    for (int a = 0; a < 4; ++a)
#pragma unroll
        for (int b = 0; b < 4; ++b) acc[a][b] = fzero;

    GEMM_TILE_LOOP(A, Bt)

    const float QSCL = 0.18033688f;   // 0.125 * log2(e), folded into q
#pragma unroll
    for (int mf = 0; mf < 4; ++mf)
#pragma unroll
        for (int nf = 0; nf < 4; ++nf) {
            int n = n0 + wc * 64 + nf * 16 + row;
            int part = n >> 10;  // 0=q 1=k 2=v (uniform per block)
            int d = n & 1023;
            int h = d >> 6, hd = d & 63;
            float bv = bias[n];
#pragma unroll
            for (int i = 0; i < 4; ++i) {
                int mm = m0 + wr * 64 + mf * 16 + g * 4 + i;
                int b = mm >> 11, l = mm & 2047;
                float fv = acc[mf][nf][i] + bv;
                if (part == 0)
                    qo[(((size_t)(b * 16 + h) * 2048) + l) * 64 + hd] =
                        (__bf16)(fv * QSCL);
                else if (part == 1)
                    ko[(((size_t)(b * 16 + h) * 2048) + l) * 64 + hd] = (__bf16)fv;
                else
                    vt[(((size_t)(b * 16 + h) * 64) + hd) * 2048 + l] = (__bf16)fv;
            }
        }
}

// Proj: A=y[8192][1024](bf16), Bt=wprojT[1024][1024](bf16), fp32 out + bias.
__global__ __launch_bounds__(256, 2)
void proj_gemm_kernel(const __bf16* __restrict__ A, const __bf16* __restrict__ Bt,
                      const float* __restrict__ bias, float* __restrict__ out)
{
    __shared__ __bf16 As[128 * 32];
    __shared__ __bf16 Bs[128 * 32];
    const int tid = threadIdx.x;
    const int lane = tid & 63;
    const int w = tid >> 6;
    const int wr = w >> 1, wc = w & 1;
    const int row = lane & 15, g = lane >> 4;
    const int m0 = blockIdx.x * 128;
    const int n0 = blockIdx.y * 128;

    const f32x4 fzero = {0.f, 0.f, 0.f, 0.f};
    f32x4 acc[4][4];
#pragma unroll
    for (int a = 0; a < 4; ++a)
#pragma unroll
        for (int b = 0; b < 4; ++b) acc[a][b] = fzero;

    GEMM_TILE_LOOP(A, Bt)

#pragma unroll
    for (int mf = 0; mf < 4; ++mf)
#pragma unroll
        for (int nf = 0; nf < 4; ++nf) {
            int n = n0 + wc * 64 + nf * 16 + row;
            float bv = bias[n];
#pragma unroll
            for (int i = 0; i < 4; ++i) {
                int mm = m0 + wr * 64 + mf * 16 + g * 4 + i;
                out[(size_t)mm * 1024 + n] = acc[mf][nf][i] + bv;
            }
        }
}

// ---------------------------------------------------------------------------
// Pair-balanced LDS-free swapped-operand causal flash attention.
// Grid (16, B*H=64), 128 thr = 2 waves. Wave (block x, wv) owns q-tiles
// t = 2x+wv and 63-t -> every wave does exactly 65 k-tile MFMA units.
// S^T = mfma32(K, Qscaled): lane owns q-col = lane&31, 16 k per lane
// (k = (r&3)+8*(r>>2)+4*hi); partner lane (l^32) holds the other 16.
// O^T = mfma32(V^T, P^T): same q-col per lane -> m/l/alpha all lane-local.
// Q pre-scaled by 0.125*log2(e): p = exp2(s - m) directly.
// ---------------------------------------------------------------------------
__global__ __launch_bounds__(128, 2)
void attn_kernel(const __bf16* __restrict__ Qw, const __bf16* __restrict__ Kw,
                 const __bf16* __restrict__ Vt, __bf16* __restrict__ Yw)
{
    const int tid = threadIdx.x;
    const int lane = tid & 63;
    const int wv = tid >> 6;
    const int col = lane & 31;
    const int hi = lane >> 5;
    const int bh = blockIdx.y;
    const int t = blockIdx.x * 2 + wv;        // 0..31
    const int qA = t * 32;                    // low q-tile
    const int qB = (63 - t) * 32;             // high q-tile
    const __bf16* Q = Qw + (size_t)bh * 2048 * 64;
    const __bf16* K = Kw + (size_t)bh * 2048 * 64;
    const __bf16* V = Vt + (size_t)bh * 64 * 2048;   // [64 d][2048 k]

    bf16x8 qfA[4], qfB[4];
#pragma unroll
    for (int dc = 0; dc < 4; ++dc) {
        qfA[dc] = *(const bf16x8*)&Q[(size_t)(qA + col) * 64 + dc * 16 + hi * 8];
        qfB[dc] = *(const bf16x8*)&Q[(size_t)(qB + col) * 64 + dc * 16 + hi * 8];
    }

    f32x16 OtA[2], OtB[2];
#pragma unroll
    for (int dt = 0; dt < 2; ++dt)
#pragma unroll
        for (int i = 0; i < 16; ++i) { OtA[dt][i] = 0.f; OtB[dt][i] = 0.f; }
    float mA = -__builtin_inff(), lA = 0.f;
    float mB = -__builtin_inff(), lB = 0.f;

    // softmax+pack for one chain; st already in exp2 domain.
    auto smxpack = [&](f32x16& st, float& m, float& lsum, f32x16* Ot,
                       bool diag, bf16x8& pa0, bf16x8& pa1) {
        if (diag) {
#pragma unroll
            for (int r = 0; r < 16; ++r) {
                int crow = (r & 3) + 8 * (r >> 2) + 4 * hi;
                if (crow > col) st[r] = -1e30f;
            }
        }
        // max tree (max3-friendly)
        float a0 = fmaxf(fmaxf(st[0], st[1]), st[2]);
        float a1 = fmaxf(fmaxf(st[3], st[4]), st[5]);
        float a2 = fmaxf(fmaxf(st[6], st[7]), st[8]);
        float a3 = fmaxf(fmaxf(st[9], st[10]), st[11]);
        float a4 = fmaxf(st[12], st[13]);
        float a5 = fmaxf(st[14], st[15]);
        float pmax = fmaxf(fmaxf(fmaxf(a0, a1), fmaxf(a2, a3)), fmaxf(a4, a5));
        pmax = fmaxf(pmax, __shfl_xor(pmax, 32, 64));
        if (!__all(pmax - m <= 8.0f)) {
            float mnew = fmaxf(m, pmax);
            float alpha = exp2f(m - mnew);
#pragma unroll
            for (int dt = 0; dt < 2; ++dt)
#pragma unroll
                for (int i = 0; i < 16; ++i) Ot[dt][i] *= alpha;
            lsum *= alpha;
            m = mnew;
        }
#pragma unroll
        for (int r = 0; r < 16; ++r) st[r] = exp2f(st[r] - m);
        // pairwise sum tree
        float s0 = (st[0] + st[1]) + (st[2] + st[3]);
        float s1 = (st[4] + st[5]) + (st[6] + st[7]);
        float s2 = (st[8] + st[9]) + (st[10] + st[11]);
        float s3 = (st[12] + st[13]) + (st[14] + st[15]);
        float rs = (s0 + s1) + (s2 + s3);
        rs += __shfl_xor(rs, 32, 64);
        lsum += rs;
        // pack P^T -> B-frags
        unsigned u0 = pkbf(st[0], st[1]),   u1 = pkbf(st[2], st[3]);
        unsigned u2 = pkbf(st[4], st[5]),   u3 = pkbf(st[6], st[7]);
        unsigned u4 = pkbf(st[8], st[9]),   u5 = pkbf(st[10], st[11]);
        unsigned u6 = pkbf(st[12], st[13]), u7 = pkbf(st[14], st[15]);
        unsigned xu0 = __shfl_xor((int)u0, 32, 64), xu1 = __shfl_xor((int)u1, 32, 64);
        unsigned xu2 = __shfl_xor((int)u2, 32, 64), xu3 = __shfl_xor((int)u3, 32, 64);
        unsigned xu4 = __shfl_xor((int)u4, 32, 64), xu5 = __shfl_xor((int)u5, 32, 64);
        unsigned xu6 = __shfl_xor((int)u6, 32, 64), xu7 = __shfl_xor((int)u7, 32, 64);
        u32x4 w0 = {hi ? xu2 : u0, hi ? xu3 : u1, hi ? u2 : xu0, hi ? u3 : xu1};
        u32x4 w1 = {hi ? xu6 : u4, hi ? xu7 : u5, hi ? u6 : xu4, hi ? u7 : xu5};
        pa0 = __builtin_bit_cast(bf16x8, w0);
        pa1 = __builtin_bit_cast(bf16x8, w1);
    };

    for (int kb = 0; kb <= qB; kb += 32) {
        const bool dual = (kb <= qA);
        bf16x8 kf[4];
#pragma unroll
        for (int dc = 0; dc < 4; ++dc)
            kf[dc] = *(const bf16x8*)&K[(size_t)(kb + col) * 64 + dc * 16 + hi * 8];

        f32x16 stA, stB;
#pragma unroll
        for (int i = 0; i < 16; ++i) { stA[i] = 0.f; stB[i] = 0.f; }
        __builtin_amdgcn_s_setprio(1);
        if (dual) {
#pragma unroll
            for (int dc = 0; dc < 4; ++dc) {
                stB = MFMA32(kf[dc], qfB[dc], stB);
                stA = MFMA32(kf[dc], qfA[dc], stA);
            }
        } else {
#pragma unroll
            for (int dc = 0; dc < 4; ++dc)
                stB = MFMA32(kf[dc], qfB[dc], stB);
        }
        __builtin_amdgcn_s_setprio(0);

        bf16x8 paA0, paA1, paB0, paB1;
        smxpack(stB, mB, lB, OtB, kb == qB, paB0, paB1);
        if (dual) smxpack(stA, mA, lA, OtA, kb == qA, paA0, paA1);

        __builtin_amdgcn_s_setprio(1);
#pragma unroll
        for (int dt = 0; dt < 2; ++dt) {
            bf16x8 v0 = *(const bf16x8*)&V[(size_t)(dt * 32 + col) * 2048 + kb + hi * 8];
            bf16x8 v1 = *(const bf16x8*)&V[(size_t)(dt * 32 + col) * 2048 + kb + 16 + hi * 8];
            OtB[dt] = MFMA32(v0, paB0, OtB[dt]);
            OtB[dt] = MFMA32(v1, paB1, OtB[dt]);
            if (dual) {
                OtA[dt] = MFMA32(v0, paA0, OtA[dt]);
                OtA[dt] = MFMA32(v1, paA1, OtA[dt]);
            }
        }
        __builtin_amdgcn_s_setprio(0);
    }

    // ---- epilogue: O^T C-layout col=q(lane-local), d = dt*32+8*(r>>2)+4*hi+(r&3)
    const int b = bh >> 4, h = bh & 15;
    const float invA = 1.f / lA, invB = 1.f / lB;
    __bf16* yrowA = Yw + ((size_t)(b * 2048 + qA + col)) * 1024 + h * 64;
    __bf16* yrowB = Yw + ((size_t)(b * 2048 + qB + col)) * 1024 + h * 64;
#pragma unroll
    for (int dt = 0; dt < 2; ++dt)
#pragma unroll
        for (int rg = 0; rg < 4; ++rg) {
            int d0 = dt * 32 + rg * 8 + hi * 4;
            unsigned lo = pkbf(OtA[dt][rg * 4 + 0] * invA, OtA[dt][rg * 4 + 1] * invA);
            unsigned h2 = pkbf(OtA[dt][rg * 4 + 2] * invA, OtA[dt][rg * 4 + 3] * invA);
            *(unsigned long long*)&yrowA[d0] =
                (unsigned long long)lo | ((unsigned long long)h2 << 32);
            lo = pkbf(OtB[dt][rg * 4 + 0] * invB, OtB[dt][rg * 4 + 1] * invB);
            h2 = pkbf(OtB[dt][rg * 4 + 2] * invB, OtB[dt][rg * 4 + 3] * invB);
            *(unsigned long long*)&yrowB[d0] =
                (unsigned long long)lo | ((unsigned long long)h2 << 32);
        }
}

// ---------------------------------------------------------------------------
extern "C" void kernel_launch(void* const* d_in, const int* in_sizes, int n_in,
                              void* d_out, int out_size, void* d_ws, size_t ws_size,
                              hipStream_t stream)
{
    const float* x     = (const float*)d_in[0];
    const float* wqkv  = (const float*)d_in[1];
    const float* bqkv  = (const float*)d_in[2];
    const float* wproj = (const float*)d_in[3];
    const float* bproj = (const float*)d_in[4];
    float* out = (float*)d_out;

    const size_t E = (size_t)4 * 16 * 2048 * 64;  // 8,388,608 per [B,H,L,64] tensor
    __bf16* q      = (__bf16*)d_ws;               // E (pre-scaled)
    __bf16* k      = q + E;                       // E
    __bf16* vt     = k + E;                       // E ([B,H,64,L])
    __bf16* xb     = vt + E;                      // E  (x bf16)
    __bf16* y      = xb;                          // alias: y written after xb consumed
    __bf16* wqkvT  = xb + E;                      // 3072*1024
    __bf16* wprojT = wqkvT + (size_t)3072 * 1024; // 1024*1024

    convert_kernel<<<4096, 256, 0, stream>>>(x, xb);
    transpose_convert_kernel<<<dim3(96, 32), 256, 0, stream>>>(wqkv, wqkvT, 1024, 3072);
    transpose_convert_kernel<<<dim3(32, 32), 256, 0, stream>>>(wproj, wprojT, 1024, 1024);
    qkv_gemm_kernel<<<dim3(64, 24), 256, 0, stream>>>(xb, wqkvT, bqkv, q, k, vt);
    attn_kernel<<<dim3(16, 64), 128, 0, stream>>>(q, k, vt, y);
    proj_gemm_kernel<<<dim3(64, 8), 256, 0, stream>>>(y, wprojT, bproj, out);
}

// Round 7
// 240.183 us; speedup vs baseline: 2.6611x; 1.0346x over previous
//
#include <hip/hip_runtime.h>

// B=4, L=2048, D=1024, H=16, HD=64.
// d_in fp32: x, Wqkv, bqkv, Wproj, bproj. d_out fp32.
// Pipeline: one-time fp32->bf16 conversion (X straight; W transposed k-major),
// m97-style bf16 MFMA GEMMs with global_load_lds, and swapped-operand LDS-free
// causal flash attention, anti-diagonal pair-balanced, zero-shuffle P pack via
// bit2<->bit3-permuted V^T storage, K/V software prefetch.

typedef __bf16 bf16x8 __attribute__((ext_vector_type(8)));
typedef float f32x4 __attribute__((ext_vector_type(4)));
typedef float f32x16 __attribute__((ext_vector_type(16)));
typedef unsigned u32x4 __attribute__((ext_vector_type(4)));

#define MFMA16(a, b, c) __builtin_amdgcn_mfma_f32_16x16x32_bf16(a, b, c, 0, 0, 0)
#define MFMA32(a, b, c) __builtin_amdgcn_mfma_f32_32x32x16_bf16(a, b, c, 0, 0, 0)

__device__ __forceinline__ void gload_lds16(const __bf16* g, __bf16* l) {
    __builtin_amdgcn_global_load_lds(
        (const __attribute__((address_space(1))) void*)g,
        (__attribute__((address_space(3))) void*)l, 16, 0, 0);
}

__device__ __forceinline__ unsigned pkbf(float a, float b) {
    unsigned short ua = __builtin_bit_cast(unsigned short, (__bf16)a);
    unsigned short ub = __builtin_bit_cast(unsigned short, (__bf16)b);
    return (unsigned)ua | ((unsigned)ub << 16);
}

// ---------------------------------------------------------------------------
// fp32 -> bf16 straight convert (n multiple of 2048)
// ---------------------------------------------------------------------------
__global__ void convert_kernel(const float* __restrict__ in, __bf16* __restrict__ out)
{
    int i = (blockIdx.x * 256 + threadIdx.x) * 8;
    f32x4 lo = *(const f32x4*)&in[i];
    f32x4 hi = *(const f32x4*)&in[i + 4];
    bf16x8 o;
#pragma unroll
    for (int j = 0; j < 4; ++j) { o[j] = (__bf16)lo[j]; o[j + 4] = (__bf16)hi[j]; }
    *(bf16x8*)&out[i] = o;
}

// ---------------------------------------------------------------------------
// fp32 [R][C] -> bf16 [C][R] transpose-convert. Grid (C/32, R/32), 256 thr.
// ---------------------------------------------------------------------------
__global__ void transpose_convert_kernel(const float* __restrict__ in,
                                         __bf16* __restrict__ out, int R, int C)
{
    __shared__ __bf16 t[32][33];
    const int c0 = blockIdx.x * 32, r0 = blockIdx.y * 32;
    const int tx = threadIdx.x & 31, ty = threadIdx.x >> 5;
#pragma unroll
    for (int j = 0; j < 4; ++j) {
        int r = ty + j * 8;
        t[tx][r] = (__bf16)in[(size_t)(r0 + r) * C + c0 + tx];
    }
    __syncthreads();
#pragma unroll
    for (int j = 0; j < 4; ++j) {
        int r = ty + j * 8;
        out[(size_t)(c0 + r) * R + r0 + tx] = t[r][tx];
    }
}

// ---------------------------------------------------------------------------
// m97-style GEMM core: C[m][n] = A[m][k] * Bt[n][k], 128x128 tile, BK=32,
// 4 waves (2x2). global_load_lds(16B) linear dest; source chunk pre-swizzled
// with s(r) = (r>>1)&3 and frag reads apply the same XOR (involution).
// ---------------------------------------------------------------------------
#define GEMM_TILE_LOOP(Abase, Bbase)                                               \
    for (int k0 = 0; k0 < 1024; k0 += 32) {                                        \
        __syncthreads();                                                           \
        _Pragma("unroll")                                                          \
        for (int i = 0; i < 2; ++i) {                                              \
            int wl = w * 2 + i;                                                    \
            int r = wl * 16 + (lane >> 2);                                         \
            int c = ((lane & 3) ^ ((r >> 1) & 3)) * 8;                             \
            gload_lds16(&Abase[(size_t)(m0 + r) * 1024 + k0 + c], &As[wl * 512]);  \
            gload_lds16(&Bbase[(size_t)(n0 + r) * 1024 + k0 + c], &Bs[wl * 512]);  \
        }                                                                          \
        __syncthreads();                                                           \
        bf16x8 af[4], bfr[4];                                                      \
        _Pragma("unroll")                                                          \
        for (int mf = 0; mf < 4; ++mf) {                                           \
            int rr = wr * 64 + mf * 16 + row;                                      \
            af[mf] = *(const bf16x8*)&As[rr * 32 + ((g ^ ((rr >> 1) & 3)) * 8)];   \
        }                                                                          \
        _Pragma("unroll")                                                          \
        for (int nf = 0; nf < 4; ++nf) {                                           \
            int rr = wc * 64 + nf * 16 + row;                                      \
            bfr[nf] = *(const bf16x8*)&Bs[rr * 32 + ((g ^ ((rr >> 1) & 3)) * 8)];  \
        }                                                                          \
        _Pragma("unroll")                                                          \
        for (int mf = 0; mf < 4; ++mf)                                             \
            _Pragma("unroll")                                                      \
            for (int nf = 0; nf < 4; ++nf)                                         \
                acc[mf][nf] = MFMA16(af[mf], bfr[nf], acc[mf][nf]);                \
    }

// QKV: A=xb[8192][1024], Bt=wqkvT[3072][1024]. q(SCALED),k -> [B,H,L,64];
// v -> [B,H,64,L] with k-index bits 2<->3 swapped (zero-shuffle PV pack).
__global__ __launch_bounds__(256, 2)
void qkv_gemm_kernel(const __bf16* __restrict__ A, const __bf16* __restrict__ Bt,
                     const float* __restrict__ bias,
                     __bf16* __restrict__ qo, __bf16* __restrict__ ko,
                     __bf16* __restrict__ vt)
{
    __shared__ __bf16 As[128 * 32];
    __shared__ __bf16 Bs[128 * 32];
    const int tid = threadIdx.x;
    const int lane = tid & 63;
    const int w = tid >> 6;
    const int wr = w >> 1, wc = w & 1;
    const int row = lane & 15, g = lane >> 4;
    const int m0 = blockIdx.x * 128;
    const int n0 = blockIdx.y * 128;

    const f32x4 fzero = {0.f, 0.f, 0.f, 0.f};
    f32x4 acc[4][4];
#pragma unroll
    for (int a = 0; a < 4; ++a)
#pragma unroll
        for (int b = 0; b < 4; ++b) acc[a][b] = fzero;

    GEMM_TILE_LOOP(A, Bt)

    const float QSCL = 0.18033688f;   // 0.125 * log2(e), folded into q
#pragma unroll
    for (int mf = 0; mf < 4; ++mf)
#pragma unroll
        for (int nf = 0; nf < 4; ++nf) {
            int n = n0 + wc * 64 + nf * 16 + row;
            int part = n >> 10;  // 0=q 1=k 2=v (uniform per block)
            int d = n & 1023;
            int h = d >> 6, hd = d & 63;
            float bv = bias[n];
#pragma unroll
            for (int i = 0; i < 4; ++i) {
                int mm = m0 + wr * 64 + mf * 16 + g * 4 + i;
                int b = mm >> 11, l = mm & 2047;
                float fv = acc[mf][nf][i] + bv;
                if (part == 0)
                    qo[(((size_t)(b * 16 + h) * 2048) + l) * 64 + hd] =
                        (__bf16)(fv * QSCL);
                else if (part == 1)
                    ko[(((size_t)(b * 16 + h) * 2048) + l) * 64 + hd] = (__bf16)fv;
                else {
                    // swap bits 2 and 3 of the k position (within each 32-tile)
                    int lp = (l & ~12) | ((l & 4) << 1) | ((l & 8) >> 1);
                    vt[(((size_t)(b * 16 + h) * 64) + hd) * 2048 + lp] = (__bf16)fv;
                }
            }
        }
}

// Proj: A=y[8192][1024](bf16), Bt=wprojT[1024][1024](bf16), fp32 out + bias.
__global__ __launch_bounds__(256, 2)
void proj_gemm_kernel(const __bf16* __restrict__ A, const __bf16* __restrict__ Bt,
                      const float* __restrict__ bias, float* __restrict__ out)
{
    __shared__ __bf16 As[128 * 32];
    __shared__ __bf16 Bs[128 * 32];
    const int tid = threadIdx.x;
    const int lane = tid & 63;
    const int w = tid >> 6;
    const int wr = w >> 1, wc = w & 1;
    const int row = lane & 15, g = lane >> 4;
    const int m0 = blockIdx.x * 128;
    const int n0 = blockIdx.y * 128;

    const f32x4 fzero = {0.f, 0.f, 0.f, 0.f};
    f32x4 acc[4][4];
#pragma unroll
    for (int a = 0; a < 4; ++a)
#pragma unroll
        for (int b = 0; b < 4; ++b) acc[a][b] = fzero;

    GEMM_TILE_LOOP(A, Bt)

#pragma unroll
    for (int mf = 0; mf < 4; ++mf)
#pragma unroll
        for (int nf = 0; nf < 4; ++nf) {
            int n = n0 + wc * 64 + nf * 16 + row;
            float bv = bias[n];
#pragma unroll
            for (int i = 0; i < 4; ++i) {
                int mm = m0 + wr * 64 + mf * 16 + g * 4 + i;
                out[(size_t)mm * 1024 + n] = acc[mf][nf][i] + bv;
            }
        }
}

// ---------------------------------------------------------------------------
// Pair-balanced LDS-free swapped-operand causal flash attention.
// Grid (16, B*H=64), 128 thr = 2 waves. Wave (block x, wv) owns q-tiles
// t = 2x+wv and 63-t -> every wave does exactly 65 k-tile MFMA units.
// S^T = mfma32(K, Qscaled): lane owns q-col = lane&31; st[r] holds k-row
// (r&3)+8*(r>>2)+4*hi. PV uses the SAME per-lane k placement on both
// operands (permutation invariance): pa0 = st[0..7], pa1 = st[8..15] packed
// in-lane (zero shuffles) against V^T stored with k-bits 2<->3 swapped.
// K next-tile and V current-tile loads issued early (latency hidden).
// ---------------------------------------------------------------------------
__global__ __launch_bounds__(128, 2)
void attn_kernel(const __bf16* __restrict__ Qw, const __bf16* __restrict__ Kw,
                 const __bf16* __restrict__ Vt, __bf16* __restrict__ Yw)
{
    const int tid = threadIdx.x;
    const int lane = tid & 63;
    const int wv = tid >> 6;
    const int col = lane & 31;
    const int hi = lane >> 5;
    const int bh = blockIdx.y;
    const int t = blockIdx.x * 2 + wv;        // 0..31
    const int qA = t * 32;                    // low q-tile
    const int qB = (63 - t) * 32;             // high q-tile
    const __bf16* Q = Qw + (size_t)bh * 2048 * 64;
    const __bf16* K = Kw + (size_t)bh * 2048 * 64;
    const __bf16* V = Vt + (size_t)bh * 64 * 2048;   // [64 d][2048 k] (k-perm)

    bf16x8 qfA[4], qfB[4];
#pragma unroll
    for (int dc = 0; dc < 4; ++dc) {
        qfA[dc] = *(const bf16x8*)&Q[(size_t)(qA + col) * 64 + dc * 16 + hi * 8];
        qfB[dc] = *(const bf16x8*)&Q[(size_t)(qB + col) * 64 + dc * 16 + hi * 8];
    }

    f32x16 OtA[2], OtB[2];
#pragma unroll
    for (int dt = 0; dt < 2; ++dt)
#pragma unroll
        for (int i = 0; i < 16; ++i) { OtA[dt][i] = 0.f; OtB[dt][i] = 0.f; }
    float mA = -__builtin_inff(), lA = 0.f;
    float mB = -__builtin_inff(), lB = 0.f;

    // softmax + in-lane pack for one chain; st already in exp2 domain.
    auto smxpack = [&](f32x16& st, float& m, float& lsum, f32x16* Ot,
                       bool diag, bf16x8& pa0, bf16x8& pa1) {
        if (diag) {
#pragma unroll
            for (int r = 0; r < 16; ++r) {
                int crow = (r & 3) + 8 * (r >> 2) + 4 * hi;
                if (crow > col) st[r] = -1e30f;
            }
        }
        float a0 = fmaxf(fmaxf(st[0], st[1]), st[2]);
        float a1 = fmaxf(fmaxf(st[3], st[4]), st[5]);
        float a2 = fmaxf(fmaxf(st[6], st[7]), st[8]);
        float a3 = fmaxf(fmaxf(st[9], st[10]), st[11]);
        float a4 = fmaxf(st[12], st[13]);
        float a5 = fmaxf(st[14], st[15]);
        float pmax = fmaxf(fmaxf(fmaxf(a0, a1), fmaxf(a2, a3)), fmaxf(a4, a5));
        pmax = fmaxf(pmax, __shfl_xor(pmax, 32, 64));
        if (!__all(pmax - m <= 8.0f)) {
            float mnew = fmaxf(m, pmax);
            float alpha = exp2f(m - mnew);
#pragma unroll
            for (int dt = 0; dt < 2; ++dt)
#pragma unroll
                for (int i = 0; i < 16; ++i) Ot[dt][i] *= alpha;
            lsum *= alpha;
            m = mnew;
        }
#pragma unroll
        for (int r = 0; r < 16; ++r) st[r] = exp2f(st[r] - m);
        float s0 = (st[0] + st[1]) + (st[2] + st[3]);
        float s1 = (st[4] + st[5]) + (st[6] + st[7]);
        float s2 = (st[8] + st[9]) + (st[10] + st[11]);
        float s3 = (st[12] + st[13]) + (st[14] + st[15]);
        float rs = (s0 + s1) + (s2 + s3);
        rs += __shfl_xor(rs, 32, 64);
        lsum += rs;
        // in-lane pack: pa0 element j = st[j] (k = 4hi+(j&3)+8*(j>>2)), pa1 = st[8+j]
        u32x4 w0 = {pkbf(st[0], st[1]), pkbf(st[2], st[3]),
                    pkbf(st[4], st[5]), pkbf(st[6], st[7])};
        u32x4 w1 = {pkbf(st[8], st[9]), pkbf(st[10], st[11]),
                    pkbf(st[12], st[13]), pkbf(st[14], st[15])};
        pa0 = __builtin_bit_cast(bf16x8, w0);
        pa1 = __builtin_bit_cast(bf16x8, w1);
    };

    // preload K tile 0
    bf16x8 kf[4];
#pragma unroll
    for (int dc = 0; dc < 4; ++dc)
        kf[dc] = *(const bf16x8*)&K[(size_t)col * 64 + dc * 16 + hi * 8];

    for (int kb = 0; kb <= qB; kb += 32) {
        const bool dual = (kb <= qA);
        // early V loads (consumed after softmax, ~400cy later)
        bf16x8 vf[4];
#pragma unroll
        for (int dt = 0; dt < 2; ++dt) {
            vf[dt * 2 + 0] = *(const bf16x8*)&V[(size_t)(dt * 32 + col) * 2048 + kb + hi * 8];
            vf[dt * 2 + 1] = *(const bf16x8*)&V[(size_t)(dt * 32 + col) * 2048 + kb + 16 + hi * 8];
        }

        f32x16 stA, stB;
#pragma unroll
        for (int i = 0; i < 16; ++i) { stA[i] = 0.f; stB[i] = 0.f; }
        __builtin_amdgcn_s_setprio(1);
        if (dual) {
#pragma unroll
            for (int dc = 0; dc < 4; ++dc) {
                stB = MFMA32(kf[dc], qfB[dc], stB);
                stA = MFMA32(kf[dc], qfA[dc], stA);
            }
        } else {
#pragma unroll
            for (int dc = 0; dc < 4; ++dc)
                stB = MFMA32(kf[dc], qfB[dc], stB);
        }
        __builtin_amdgcn_s_setprio(0);

        // prefetch next K tile (kf regs now free; needed next iteration)
        const int kn = (kb + 32 <= qB) ? kb + 32 : qB;
        bf16x8 kfn[4];
#pragma unroll
        for (int dc = 0; dc < 4; ++dc)
            kfn[dc] = *(const bf16x8*)&K[(size_t)(kn + col) * 64 + dc * 16 + hi * 8];

        bf16x8 paA0, paA1, paB0, paB1;
        smxpack(stB, mB, lB, OtB, kb == qB, paB0, paB1);
        if (dual) smxpack(stA, mA, lA, OtA, kb == qA, paA0, paA1);

        __builtin_amdgcn_s_setprio(1);
#pragma unroll
        for (int dt = 0; dt < 2; ++dt) {
            OtB[dt] = MFMA32(vf[dt * 2 + 0], paB0, OtB[dt]);
            OtB[dt] = MFMA32(vf[dt * 2 + 1], paB1, OtB[dt]);
            if (dual) {
                OtA[dt] = MFMA32(vf[dt * 2 + 0], paA0, OtA[dt]);
                OtA[dt] = MFMA32(vf[dt * 2 + 1], paA1, OtA[dt]);
            }
        }
        __builtin_amdgcn_s_setprio(0);

#pragma unroll
        for (int dc = 0; dc < 4; ++dc) kf[dc] = kfn[dc];
    }

    // ---- epilogue: O^T C-layout col=q(lane-local), d = dt*32+8*(r>>2)+4*hi+(r&3)
    const int b = bh >> 4, h = bh & 15;
    const float invA = 1.f / lA, invB = 1.f / lB;
    __bf16* yrowA = Yw + ((size_t)(b * 2048 + qA + col)) * 1024 + h * 64;
    __bf16* yrowB = Yw + ((size_t)(b * 2048 + qB + col)) * 1024 + h * 64;
#pragma unroll
    for (int dt = 0; dt < 2; ++dt)
#pragma unroll
        for (int rg = 0; rg < 4; ++rg) {
            int d0 = dt * 32 + rg * 8 + hi * 4;
            unsigned lo = pkbf(OtA[dt][rg * 4 + 0] * invA, OtA[dt][rg * 4 + 1] * invA);
            unsigned h2 = pkbf(OtA[dt][rg * 4 + 2] * invA, OtA[dt][rg * 4 + 3] * invA);
            *(unsigned long long*)&yrowA[d0] =
                (unsigned long long)lo | ((unsigned long long)h2 << 32);
            lo = pkbf(OtB[dt][rg * 4 + 0] * invB, OtB[dt][rg * 4 + 1] * invB);
            h2 = pkbf(OtB[dt][rg * 4 + 2] * invB, OtB[dt][rg * 4 + 3] * invB);
            *(unsigned long long*)&yrowB[d0] =
                (unsigned long long)lo | ((unsigned long long)h2 << 32);
        }
}

// ---------------------------------------------------------------------------
extern "C" void kernel_launch(void* const* d_in, const int* in_sizes, int n_in,
                              void* d_out, int out_size, void* d_ws, size_t ws_size,
                              hipStream_t stream)
{
    const float* x     = (const float*)d_in[0];
    const float* wqkv  = (const float*)d_in[1];
    const float* bqkv  = (const float*)d_in[2];
    const float* wproj = (const float*)d_in[3];
    const float* bproj = (const float*)d_in[4];
    float* out = (float*)d_out;

    const size_t E = (size_t)4 * 16 * 2048 * 64;  // 8,388,608 per [B,H,L,64] tensor
    __bf16* q      = (__bf16*)d_ws;               // E (pre-scaled)
    __bf16* k      = q + E;                       // E
    __bf16* vt     = k + E;                       // E ([B,H,64,L], k-bit-perm)
    __bf16* xb     = vt + E;                      // E  (x bf16)
    __bf16* y      = xb;                          // alias: y written after xb consumed
    __bf16* wqkvT  = xb + E;                      // 3072*1024
    __bf16* wprojT = wqkvT + (size_t)3072 * 1024; // 1024*1024

    convert_kernel<<<4096, 256, 0, stream>>>(x, xb);
    transpose_convert_kernel<<<dim3(96, 32), 256, 0, stream>>>(wqkv, wqkvT, 1024, 3072);
    transpose_convert_kernel<<<dim3(32, 32), 256, 0, stream>>>(wproj, wprojT, 1024, 1024);
    qkv_gemm_kernel<<<dim3(64, 24), 256, 0, stream>>>(xb, wqkvT, bqkv, q, k, vt);
    attn_kernel<<<dim3(16, 64), 128, 0, stream>>>(q, k, vt, y);
    proj_gemm_kernel<<<dim3(64, 8), 256, 0, stream>>>(y, wprojT, bproj, out);
}